// Round 2
// 396.358 us; speedup vs baseline: 1.1056x; 1.1056x over previous
//
#include <hip/hip_runtime.h>
#include <hip/hip_bf16.h>
#include <math.h>

// WindowAttention on MI355X — round 5: round-4 VALU-diet attention + fix.
// Round-4 NaN root cause: removing the explicit (col<49) select let garbage
// from uninitialized sK rows 49..63 reach acc; NaN/Inf garbage survives the
// fma with the -1e30 wmp pad (NaN + -1e30 = NaN) => e0 = NaN in VALID rows.
// Fix: zero sK rows 49..63 during phase A (300 dwords, disjoint from staging
// writes) so pad-column acc == 0 exactly and e0 = exp2(-1e30) = 0.
// Everything else unchanged from round 4:
//  - prepass folds (wmask + rel-pos-bias)*log2e into padded (64,8,64,64),
//    -1e30 in rows/cols >= 49 => attn mask loads are pure immediate-offset.
//  - prepass stores exp(fg), exp(bg) => 16 v_exp per thread instead of 48.
//  - softmax drops max-subtraction (logits bounded, fp32 exp2 safe).
//  - attn block swizzle: 8 heads of one b land on one XCD (fg/bg L2-local).
//  - GEMMs: bijective XCD swizzle grouping same-A-panel blocks per XCD.

#define B_TOT   2048
#define NTOK    49
#define CDIM    256
#define NHEAD   8
#define HDIM    32
#define MROWS   (B_TOT * NTOK)   // 100352
#define QKV_N   (3 * CDIM)       // 768

#define LOG2E 1.4426950408889634f

#if __has_builtin(__builtin_amdgcn_exp2f)
#define EXP2(x) __builtin_amdgcn_exp2f(x)
#else
#define EXP2(x) __expf((x) * 0.6931471805599453f)
#endif

typedef __attribute__((ext_vector_type(8))) short short8;   // 8 bf16 (4 VGPRs)
typedef __attribute__((ext_vector_type(4))) float floatx4;  // MFMA acc

typedef unsigned int u32_g __attribute__((address_space(1)));
typedef unsigned int u32_l __attribute__((address_space(3)));

__device__ __forceinline__ void gld_lds16(const void* g, void* l) {
    __builtin_amdgcn_global_load_lds((const u32_g*)g, (u32_l*)l, 16, 0, 0);
}

// ---------------------------------------------------------------------------
// cast fp32 -> bf16, 8 elems/thread.
// ---------------------------------------------------------------------------
__global__ __launch_bounds__(256) void cast_kernel(
    const float* __restrict__ in, __hip_bfloat16* __restrict__ out, int n8)
{
    const int i = blockIdx.x * 256 + threadIdx.x;
    if (i >= n8) return;
    const float4* p = (const float4*)in + (size_t)i * 2;
    float4 a = p[0], b = p[1];
    __hip_bfloat16 r[8];
    r[0] = __float2bfloat16(a.x); r[1] = __float2bfloat16(a.y);
    r[2] = __float2bfloat16(a.z); r[3] = __float2bfloat16(a.w);
    r[4] = __float2bfloat16(b.x); r[5] = __float2bfloat16(b.y);
    r[6] = __float2bfloat16(b.z); r[7] = __float2bfloat16(b.w);
    *(uint4*)(out + (size_t)i * 8) = *(const uint4*)r;
}

// ---------------------------------------------------------------------------
// prepass A: wmp[win][h][row64][col64] = (wmask + rel_pos_bias) * log2e,
// padded with -1e30 for row>=49 or col>=49. 2M elems, 8 MB.
// ---------------------------------------------------------------------------
__global__ __launch_bounds__(256) void prep_wmask(
    const float* __restrict__ wmask,   // (64, 49, 49)
    const float* __restrict__ table,   // (169, 8)
    float* __restrict__ wmp)           // (64, 8, 64, 64)
{
    const int idx = blockIdx.x * 256 + threadIdx.x;  // < 2^21
    const int col = idx & 63, row = (idx >> 6) & 63;
    const int h = (idx >> 12) & 7, win = idx >> 15;
    float v = -1e30f;
    if (row < 49 && col < 49) {
        const int qi = row / 7, qj = row % 7;
        const int ki = col / 7, kj = col % 7;
        const int ti = (qi - ki + 6) * 13 + (qj - kj + 6);
        v = (wmask[win * 2401 + row * 49 + col] + table[ti * 8 + h]) * LOG2E;
    }
    wmp[idx] = v;
}

// ---------------------------------------------------------------------------
// prepass B: out = exp(in), float4. Grid sized exactly (n % 1024 == 0).
// ---------------------------------------------------------------------------
__global__ __launch_bounds__(256) void prep_expmask(
    const float* __restrict__ in, float* __restrict__ out)
{
    const int i = blockIdx.x * 256 + threadIdx.x;
    float4 a = ((const float4*)in)[i];
    float4 r;
    r.x = EXP2(a.x * LOG2E); r.y = EXP2(a.y * LOG2E);
    r.z = EXP2(a.z * LOG2E); r.w = EXP2(a.w * LOG2E);
    ((float4*)out)[i] = r;
}

// ---------------------------------------------------------------------------
// MFMA GEMM: Y(M,NDIM) = A(M,256) @ W(NDIM,256)^T + bias.
// Bijective XCD swizzle so the NBX blocks sharing an A-panel land on one XCD.
// ---------------------------------------------------------------------------
template<int NDIM, bool OUT_BF16>
__global__ __launch_bounds__(256) void gemm_mfma(
    const __hip_bfloat16* __restrict__ A,
    const __hip_bfloat16* __restrict__ W,
    const float* __restrict__ bias,
    void* __restrict__ Yv)
{
    const int K = 256;
    __shared__ short As[128 * 64];
    __shared__ short Bs[128 * 64];
    const int t = threadIdx.x;
    const int lane = t & 63, w = t >> 6;
    const int wr = w >> 1, wc = w & 1;
    const int q = lane >> 4, l15 = lane & 15;

    constexpr int NBX = NDIM / 128;          // grid x
    constexpr int NWG = NBX * (MROWS / 128); // total blocks, % 8 == 0
    int bid = blockIdx.y * NBX + blockIdx.x; // HW dispatch linearization
    bid = (bid & 7) * (NWG >> 3) + (bid >> 3);  // chunk-per-XCD, bijective
    const int m0 = (bid / NBX) * 128, n0 = (bid % NBX) * 128;

    const int srow = t >> 3, skb = t & 7;
    const int gkb = skb ^ (srow & 7);
    const __hip_bfloat16* Ag = A + (size_t)(m0 + srow) * K + gkb * 8;
    const __hip_bfloat16* Wg = W + (size_t)(n0 + srow) * K + gkb * 8;

    floatx4 acc[4][4] = {};
    const int swz = l15 & 7;

    for (int k0 = 0; k0 < K; k0 += 64) {
        __syncthreads();
        #pragma unroll
        for (int i = 0; i < 4; i++) {
            gld_lds16(Ag + (size_t)(i * 32) * K + k0, &As[i * 2048 + w * 512]);
            gld_lds16(Wg + (size_t)(i * 32) * K + k0, &Bs[i * 2048 + w * 512]);
        }
        __syncthreads();
        #pragma unroll
        for (int kk = 0; kk < 2; kk++) {
            const int kbs = ((kk << 2) + q) ^ swz;
            short8 af[4], bf[4];
            #pragma unroll
            for (int i = 0; i < 4; i++) {
                af[i] = *(const short8*)&As[(wr * 64 + i * 16 + l15) * 64 + kbs * 8];
                bf[i] = *(const short8*)&Bs[(wc * 64 + i * 16 + l15) * 64 + kbs * 8];
            }
            #pragma unroll
            for (int i = 0; i < 4; i++)
                #pragma unroll
                for (int j = 0; j < 4; j++)
                    acc[i][j] = __builtin_amdgcn_mfma_f32_16x16x32_bf16(
                        af[i], bf[j], acc[i][j], 0, 0, 0);
        }
    }

    #pragma unroll
    for (int j = 0; j < 4; j++) {
        const int n = n0 + wc * 64 + j * 16 + l15;
        const float bv = bias[n];
        #pragma unroll
        for (int i = 0; i < 4; i++) {
            #pragma unroll
            for (int r = 0; r < 4; r++) {
                const int m = m0 + wr * 64 + i * 16 + q * 4 + r;
                const float val = acc[i][j][r] + bv;
                if (OUT_BF16)
                    ((__hip_bfloat16*)Yv)[(size_t)m * NDIM + n] = __float2bfloat16(val);
                else
                    ((float*)Yv)[(size_t)m * NDIM + n] = val;
            }
        }
    }
}

// ---------------------------------------------------------------------------
// MFMA attention, one block (4 waves) per (b,h). 2 barriers.
// LDS (24.1 KB): sQ 64x40 bf16 | sK 64x40 | sVt 32x72 (V^T, k-pad zeroed) |
//                sP 64x72 bf16.
// Phase A: prefetch wmp/Fg/Bg -> 48 VGPRs (imm-offset loads, no selects);
//          stage Q/K/Vt; zero sK rows 49..63; zero Vt k-pad.
// Phase B: S = QK^T (regs); e0 = exp2(fma(S, scale*log2e, wmp)); ef = e0*Fg;
//          eb = e0*Bg; 3 sum-reductions (4-step quad-local shuffles); rcp;
//          pc = e0*r0 + ef*rf - eb*rb -> sP bf16. No max-subtraction.
// Phase C: O = P @ V -> global bf16.
// Garbage policy: sK pad rows zeroed => pad-col acc == 0 => e0 = 2^-1e30 = 0
// exactly (kills pad cols). Garbage Q rows -> NaN in sP rows >= 49 only ->
// discarded at bounds-checked store. Vt k in [49,64] zeroed (0*NaN trap).
// fg/bg loads row-clamped (in-bounds); nt=3 col fixed at 48 (lanes l15>0
// there read a wrong-but-finite value, multiplied by e0 == 0).
// Block swizzle: b = (blk>>6)*8 + (blk&7), h = (blk>>3)&7  => the 8 heads of
// one b share an XCD (fg/bg become L2-local).
// ---------------------------------------------------------------------------
__global__ __launch_bounds__(256, 4) void attn_kernel(
    const __hip_bfloat16* __restrict__ Y,   // (B*49, 768) bf16
    const float* __restrict__ wmp,          // (64, 8, 64, 64) prepped
    const float* __restrict__ Fgp,          // (B, 49, 49) = exp(fg)
    const float* __restrict__ Bgp,          // (B, 49, 49) = exp(bg)
    __hip_bfloat16* __restrict__ O)         // (B*49, 256) bf16 -> ws
{
    __shared__ __hip_bfloat16 sQ[64 * 40];
    __shared__ __hip_bfloat16 sK[64 * 40];
    __shared__ __hip_bfloat16 sVt[32 * 72];
    __shared__ __hip_bfloat16 sP[64 * 72];

    const int blk = blockIdx.x;
    const int b = (blk >> 6) * 8 + (blk & 7);
    const int h = (blk >> 3) & 7;
    const int t = threadIdx.x;
    const int w = t >> 6, lane = t & 63;
    const int quad = lane >> 4, l15 = lane & 15;
    const float SC = 0.17677669529663687f * LOG2E;  // hd^-0.5 * log2e

    // ---- phase A ----
    // mask prefetch into registers (issued first; latency overlaps staging).
    const float* wmb = wmp + (((size_t)(b & 63) * 8 + h) << 12);
    const float* fgb = Fgp + (size_t)b * (NTOK * NTOK);
    const float* bgb = Bgp + (size_t)b * (NTOK * NTOK);
    float mwm[16], mfg[16], mbg[16];
    #pragma unroll
    for (int r = 0; r < 4; r++) {
        const int row = w * 16 + quad * 4 + r;
        const int rc49 = min(row, 48) * 49;
        const float* pw = wmb + row * 64 + l15;
        const float* pf = fgb + rc49 + l15;
        const float* pb = bgb + rc49 + l15;
        mwm[r * 4 + 0] = pw[0];  mwm[r * 4 + 1] = pw[16];
        mwm[r * 4 + 2] = pw[32]; mwm[r * 4 + 3] = pw[48];
        mfg[r * 4 + 0] = pf[0];  mfg[r * 4 + 1] = pf[16];
        mfg[r * 4 + 2] = pf[32]; mfg[r * 4 + 3] = fgb[rc49 + 48];
        mbg[r * 4 + 0] = pb[0];  mbg[r * 4 + 1] = pb[16];
        mbg[r * 4 + 2] = pb[32]; mbg[r * 4 + 3] = bgb[rc49 + 48];
    }
    // stage Q, K row-major (stride 40); V transposed (stride 72)
    const __hip_bfloat16* Yb = Y + (size_t)b * NTOK * QKV_N + h * HDIM;
    if (t < 196) {
        const int n = t >> 2, c = t & 3;  // row, 8-elem chunk
        uint4 qv = *(const uint4*)(Yb + (size_t)n * QKV_N + c * 8);
        uint4 kv = *(const uint4*)(Yb + (size_t)n * QKV_N + 256 + c * 8);
        uint4 vv = *(const uint4*)(Yb + (size_t)n * QKV_N + 512 + c * 8);
        *(uint4*)(sQ + n * 40 + c * 8) = qv;
        *(uint4*)(sK + n * 40 + c * 8) = kv;
        const __hip_bfloat16* vp = (const __hip_bfloat16*)&vv;
        #pragma unroll
        for (int j = 0; j < 8; j++)
            sVt[(c * 8 + j) * 72 + n] = vp[j];
    }
    // zero sK rows 49..63 (flat dwords [980,1280); disjoint from staging
    // writes which cover dwords < 980). Kills garbage-K NaN/Inf leak.
    {
        unsigned int* pK = (unsigned int*)sK;
        #pragma unroll
        for (int i = 980 + t; i < 1280; i += 256) pK[i] = 0u;
    }
    // zero Vt k-pad: cols 49..64 of 32 rows (512 elems; col 64 harmless).
    {
        const __hip_bfloat16 z = __float2bfloat16(0.f);
        #pragma unroll
        for (int it = 0; it < 2; it++) {
            const int idx = t + it * 256;  // 0..511
            const int d = idx >> 4, c = 49 + (idx & 15);
            sVt[d * 72 + c] = z;
        }
    }
    __syncthreads();

    // ---- phase B: S = Q K^T in registers ----
    floatx4 acc[4];
    {
        short8 af = *(const short8*)(sQ + (w * 16 + l15) * 40 + quad * 8);
        #pragma unroll
        for (int nt = 0; nt < 4; nt++) {
            short8 bf = *(const short8*)(sK + (nt * 16 + l15) * 40 + quad * 8);
            floatx4 z = {};
            acc[nt] = __builtin_amdgcn_mfma_f32_16x16x32_bf16(af, bf, z, 0, 0, 0);
        }
    }

    // unnormalized exponentials (exp2 domain; wmp pre-scaled by log2e).
    float e0[16];
    #pragma unroll
    for (int r = 0; r < 4; r++)
        #pragma unroll
        for (int nt = 0; nt < 4; nt++)
            e0[r * 4 + nt] = EXP2(fmaf(acc[nt][r], SC, mwm[r * 4 + nt]));
    #pragma unroll
    for (int i = 0; i < 16; i++) mfg[i] *= e0[i];   // ef
    #pragma unroll
    for (int i = 0; i < 16; i++) mbg[i] *= e0[i];   // eb

    // 3 row-sum reductions, quad-local 4-step shuffles (interleaved for ILP).
    float s0[4], sf[4], sb[4];
    #pragma unroll
    for (int r = 0; r < 4; r++) {
        s0[r] = (e0[r * 4] + e0[r * 4 + 1]) + (e0[r * 4 + 2] + e0[r * 4 + 3]);
        sf[r] = (mfg[r * 4] + mfg[r * 4 + 1]) + (mfg[r * 4 + 2] + mfg[r * 4 + 3]);
        sb[r] = (mbg[r * 4] + mbg[r * 4 + 1]) + (mbg[r * 4 + 2] + mbg[r * 4 + 3]);
    }
    #pragma unroll
    for (int st = 1; st < 16; st <<= 1)
        #pragma unroll
        for (int r = 0; r < 4; r++) {
            s0[r] += __shfl_xor(s0[r], st);
            sf[r] += __shfl_xor(sf[r], st);
            sb[r] += __shfl_xor(sb[r], st);
        }

    float pc[16];
    #pragma unroll
    for (int r = 0; r < 4; r++) {
        const float r0 = __builtin_amdgcn_rcpf(s0[r]);
        const float rf = __builtin_amdgcn_rcpf(sf[r]);
        const float rb = -__builtin_amdgcn_rcpf(sb[r]);
        #pragma unroll
        for (int nt = 0; nt < 4; nt++) {
            const int i = r * 4 + nt;
            pc[i] = fmaf(mbg[i], rb, fmaf(mfg[i], rf, e0[i] * r0));
        }
    }

    // P -> LDS (bf16, row-major stride 72 = A-operand layout for PV).
    #pragma unroll
    for (int r = 0; r < 4; r++) {
        const int row = w * 16 + quad * 4 + r;
        #pragma unroll
        for (int nt = 0; nt < 4; nt++)
            sP[row * 72 + nt * 16 + l15] = __float2bfloat16(pc[r * 4 + nt]);
    }
    __syncthreads();

    // ---- phase C: O = P @ V ----
    floatx4 o0 = {}, o1 = {};
    {
        short8 a0  = *(const short8*)(sP + (w * 16 + l15) * 72 + quad * 8);
        short8 a1  = *(const short8*)(sP + (w * 16 + l15) * 72 + 32 + quad * 8);
        short8 b00 = *(const short8*)(sVt + l15 * 72 + quad * 8);
        short8 b01 = *(const short8*)(sVt + l15 * 72 + 32 + quad * 8);
        short8 b10 = *(const short8*)(sVt + (16 + l15) * 72 + quad * 8);
        short8 b11 = *(const short8*)(sVt + (16 + l15) * 72 + 32 + quad * 8);
        o0 = __builtin_amdgcn_mfma_f32_16x16x32_bf16(a0, b00, o0, 0, 0, 0);
        o0 = __builtin_amdgcn_mfma_f32_16x16x32_bf16(a1, b01, o0, 0, 0, 0);
        o1 = __builtin_amdgcn_mfma_f32_16x16x32_bf16(a0, b10, o1, 0, 0, 0);
        o1 = __builtin_amdgcn_mfma_f32_16x16x32_bf16(a1, b11, o1, 0, 0, 0);
    }
    __hip_bfloat16* Ob = O + (size_t)b * NTOK * CDIM + h * HDIM;
    #pragma unroll
    for (int r = 0; r < 4; r++) {
        const int m = w * 16 + quad * 4 + r;
        if (m < NTOK) {
            Ob[(size_t)m * CDIM + l15]      = __float2bfloat16(o0[r]);
            Ob[(size_t)m * CDIM + 16 + l15] = __float2bfloat16(o1[r]);
        }
    }
}

extern "C" void kernel_launch(void* const* d_in, const int* in_sizes, int n_in,
                              void* d_out, int out_size, void* d_ws, size_t ws_size,
                              hipStream_t stream) {
    const float* x      = (const float*)d_in[0];
    const float* mask   = (const float*)d_in[1];
    const float* fg     = (const float*)d_in[2];
    const float* bg     = (const float*)d_in[3];
    const float* qkv_w  = (const float*)d_in[4];
    const float* qkv_b  = (const float*)d_in[5];
    const float* proj_w = (const float*)d_in[6];
    const float* proj_b = (const float*)d_in[7];
    const float* table  = (const float*)d_in[8];
    float* out = (float*)d_out;

    char* ws = (char*)d_ws;
    __hip_bfloat16* xb  = (__hip_bfloat16*)(ws);                    //  51,380,224 B
    __hip_bfloat16* Ybf = (__hip_bfloat16*)(ws + 51380224);         // 154,140,672 B
    __hip_bfloat16* Obf = (__hip_bfloat16*)(ws + 205520896);        //  51,380,224 B
    __hip_bfloat16* qwb = (__hip_bfloat16*)(ws + 256901120);        //     393,216 B
    __hip_bfloat16* pwb = (__hip_bfloat16*)(ws + 257294336);        //     131,072 B
    // prep buffers alias the xb region (xb is dead once gemm_qkv completes):
    float* wmp = (float*)(ws);                                      //   8,388,608 B
    float* Fgp = (float*)(ws + 8388608);                            //  19,668,992 B
    float* Bgp = (float*)(ws + 28057600);                           //  19,668,992 B (ends 47,726,592)

    dim3 blk(256);
    cast_kernel<<<dim3((MROWS * CDIM / 8 + 255) / 256), blk, 0, stream>>>(x, xb, MROWS * CDIM / 8);
    cast_kernel<<<dim3((QKV_N * CDIM / 8 + 255) / 256), blk, 0, stream>>>(qkv_w, qwb, QKV_N * CDIM / 8);
    cast_kernel<<<dim3((CDIM * CDIM / 8 + 255) / 256), blk, 0, stream>>>(proj_w, pwb, CDIM * CDIM / 8);

    gemm_mfma<QKV_N, true><<<dim3(QKV_N / 128, MROWS / 128), blk, 0, stream>>>(xb, qwb, qkv_b, Ybf);

    // prepasses (after gemm_qkv: they overwrite the xb region)
    prep_wmask<<<dim3(8192), blk, 0, stream>>>(mask, table, wmp);
    prep_expmask<<<dim3(4802), blk, 0, stream>>>(fg, Fgp);   // 2048*2401/4 = 4802*256
    prep_expmask<<<dim3(4802), blk, 0, stream>>>(bg, Bgp);

    attn_kernel<<<dim3(B_TOT * NHEAD), blk, 0, stream>>>(Ybf, wmp, Fgp, Bgp, Obf);
    gemm_mfma<CDIM, false><<<dim3(CDIM / 128, MROWS / 128), blk, 0, stream>>>(Obf, pwb, proj_b, out);
}